// Round 3
// baseline (236.672 us; speedup 1.0000x reference)
//
#include <hip/hip_runtime.h>
#include <hip/hip_bf16.h>

namespace {

constexpr int B = 2, S = 2048, E = 512, H = 8, D = 64, HD = 512;
constexpr float SL = 0.125f * 1.44269504f;  // (1/sqrt(64)) * log2(e)
constexpr int PLD = 40;                     // proj LDS row stride (bf16)

typedef __attribute__((ext_vector_type(8))) short bf16x8;
typedef __attribute__((ext_vector_type(4))) unsigned short u16x4;
typedef __attribute__((ext_vector_type(4))) float f32x4;
typedef __attribute__((ext_vector_type(4))) float float4v;

__device__ __forceinline__ ushort f2b(float x) {
  __hip_bfloat16 h = __float2bfloat16(x);
  return *reinterpret_cast<const ushort*>(&h);
}

// ---------------------------------------------------------------------------
// Fused prep. blocks [0,512): K/V convert+transpose; [512,640): W transpose;
// [640,8832): mask -> ballot keep bits (4096 rows x 8 chunks = 32768 waves).
// keep layout: uint4 per (row, 128k-tile); component r bit i = keep(k=tile*128+4i+r).
__global__ __launch_bounds__(256) void prep_fused_kernel(
    const float* __restrict__ K, const float* __restrict__ V,
    const float* __restrict__ Wq, const float* __restrict__ Wo,
    const int* __restrict__ maskp,
    ushort* __restrict__ Kbf, ushort* __restrict__ Vtbf,
    ushort* __restrict__ Wtq, ushort* __restrict__ Wto,
    uint4* __restrict__ keep4) {
  const int bid = blockIdx.x;
  const int t = threadIdx.x;
  if (bid < 512) {
    __shared__ __align__(16) ushort Vn[64][76];
    const int kt = bid & 31;
    const int bh = bid >> 5;
    const int b = bh >> 3, h = bh & 7;
    const int k0 = kt * 64;
#pragma unroll
    for (int i = 0; i < 4; ++i) {
      int c = i * 256 + t;
      int kk = c >> 4, d4 = (c & 15) * 4;
      size_t g = ((size_t)(b * 2048 + k0 + kk) * 8 + h) * 64 + d4;
      float4v kv = *(const float4v*)(K + g);
      float4v vv = *(const float4v*)(V + g);
      u16x4 kp = {f2b(kv.x), f2b(kv.y), f2b(kv.z), f2b(kv.w)};
      u16x4 vp = {f2b(vv.x), f2b(vv.y), f2b(vv.z), f2b(vv.w)};
      *(u16x4*)(Kbf + ((size_t)(bh * 2048 + k0 + kk)) * 64 + d4) = kp;
      *(u16x4*)&Vn[kk][d4] = vp;
    }
    __syncthreads();
#pragma unroll
    for (int i = 0; i < 2; ++i) {
      int c = i * 256 + t;
      int kc8 = (c & 7) * 8, d = c >> 3;
      union { ushort u[8]; bf16x8 v; } p;
#pragma unroll
      for (int j = 0; j < 8; ++j) p.u[j] = Vn[kc8 + j][d];
      *(bf16x8*)(Vtbf + ((size_t)(bh * 64 + d)) * 2048 + k0 + kc8) = p.v;
    }
  } else if (bid < 640) {
    __shared__ __align__(16) ushort T[64][68];
    const int idx = bid - 512;
    const float* Wsrc = (idx >> 6) ? Wo : Wq;
    ushort* Wdst = (idx >> 6) ? Wto : Wtq;
    const int x = idx & 63;
    const int k0 = (x & 7) * 64, n0 = (x >> 3) * 64;
#pragma unroll
    for (int i = 0; i < 4; ++i) {
      int c = i * 256 + t;
      int kk = c >> 4, n4 = (c & 15) * 4;
      float4v v = *(const float4v*)(Wsrc + (size_t)(k0 + kk) * 512 + n0 + n4);
      u16x4 p = {f2b(v.x), f2b(v.y), f2b(v.z), f2b(v.w)};
      *(u16x4*)&T[kk][n4] = p;
    }
    __syncthreads();
#pragma unroll
    for (int i = 0; i < 2; ++i) {
      int c = i * 256 + t;
      int n = c >> 3, k8 = (c & 7) * 8;
      union { ushort u[8]; bf16x8 v; } p;
#pragma unroll
      for (int j = 0; j < 8; ++j) p.u[j] = T[k8 + j][n];
      *(bf16x8*)(Wdst + (size_t)(n0 + n) * 512 + k0 + k8) = p.v;
    }
  } else {
    // mask: wave per 256-k chunk of one row; 4096 rows x 8 chunks
    const int wid = (bid - 640) * 4 + (t >> 6);  // 0..32767
    const int row = wid >> 3, c = wid & 7;
    const int lane = t & 63;
    const int4 v = *((const int4*)(maskp + (size_t)row * 2048 + c * 256) + lane);
    unsigned long long bx = __ballot(v.x == 0);
    unsigned long long by = __ballot(v.y == 0);
    unsigned long long bz = __ballot(v.z == 0);
    unsigned long long bw = __ballot(v.w == 0);
    if (lane == 0)
      keep4[(size_t)row * 16 + c * 2] = uint4{(uint)bx, (uint)by, (uint)bz, (uint)bw};
    if (lane == 32)
      keep4[(size_t)row * 16 + c * 2 + 1] =
          uint4{(uint)(bx >> 32), (uint)(by >> 32), (uint)(bz >> 32), (uint)(bw >> 32)};
  }
}

// ---------------------------------------------------------------------------
// proj_out: out fp32 = attnb (bf16) @ Wo, pipelined LDS staging.
__global__ __launch_bounds__(256) void proj_out_kernel(
    const ushort* __restrict__ A, const ushort* __restrict__ Wt, float* __restrict__ C) {
  __shared__ __align__(16) ushort As[64][PLD];
  __shared__ __align__(16) ushort Ws[64][PLD];

  const int tid = threadIdx.x;
  const int lane = tid & 63;
  const int w = tid >> 6;
  const int col = lane & 15;
  const int quad = lane >> 4;
  const int m0 = blockIdx.y * 64;
  const int n0 = blockIdx.x * 64;
  const int wm = (w & 1) * 32;
  const int wn = (w >> 1) * 32;
  const int ar = tid >> 2;
  const int ak = (tid & 3) * 8;
  const int wn2 = tid >> 2;
  const int wkc = (tid & 3) * 8;

  f32x4 acc[2][2];
#pragma unroll
  for (int i = 0; i < 2; ++i)
#pragma unroll
    for (int j = 0; j < 2; ++j) acc[i][j] = f32x4{0.f, 0.f, 0.f, 0.f};

  const ushort* Ap = A + (size_t)(m0 + ar) * 512 + ak;
  const ushort* Wp = Wt + (size_t)(n0 + wn2) * 512 + wkc;
  bf16x8 apre = *(const bf16x8*)Ap;
  bf16x8 wp = *(const bf16x8*)Wp;

  for (int kt = 0; kt < 16; ++kt) {
    if (kt) __syncthreads();
    *(bf16x8*)&As[ar][ak] = apre;
    *(bf16x8*)&Ws[wn2][wkc] = wp;
    if (kt < 15) {
      const int k1 = (kt + 1) * 32;
      apre = *(const bf16x8*)(Ap + k1);
      wp = *(const bf16x8*)(Wp + k1);
    }
    __syncthreads();

    bf16x8 ah[2], wb[2];
#pragma unroll
    for (int i = 0; i < 2; ++i)
      ah[i] = *(const bf16x8*)&As[wm + i * 16 + col][quad * 8];
#pragma unroll
    for (int j = 0; j < 2; ++j)
      wb[j] = *(const bf16x8*)&Ws[wn + j * 16 + col][quad * 8];
#pragma unroll
    for (int i = 0; i < 2; ++i)
#pragma unroll
      for (int j = 0; j < 2; ++j)
        acc[i][j] = __builtin_amdgcn_mfma_f32_16x16x32_bf16(ah[i], wb[j], acc[i][j], 0, 0, 0);
  }

#pragma unroll
  for (int i = 0; i < 2; ++i)
#pragma unroll
    for (int j = 0; j < 2; ++j)
#pragma unroll
      for (int r = 0; r < 4; ++r)
        C[(size_t)(m0 + wm + i * 16 + (quad << 2) + r) * 512 + n0 + wn + j * 16 + col] =
            acc[i][j][r];
}

// ---------------------------------------------------------------------------
// Flash attention, 512 threads / 128 q-rows / 1 block per CU.
// Fused Q-projection prologue (LDS); main K-loop is LDS-free and barrier-light:
// K A-frags and V B-frags are loaded straight from global into registers,
// software-pipelined one 128-k tile ahead. All 8 waves stream the same tile
// (L1 reuse), kept in loose lockstep by a raw s_barrier (no vmcnt drain).
__global__ __launch_bounds__(512, 2) void flash_attn_kernel(
    const float* __restrict__ inp, const ushort* __restrict__ Wtq,
    const ushort* __restrict__ Kbf, const ushort* __restrict__ Vtbf,
    const uint4* __restrict__ keep4, ushort* __restrict__ Op) {
  __shared__ __align__(16) ushort PQ[128][72];  // Qproj staging, then Q[128][64]

  const int bid = blockIdx.x;
  const int qt = bid & 15;
  const int bh = bid >> 4;
  const int b = bh >> 3, h = bh & 7;
  const int q0 = qt * 128;
  const int tid = threadIdx.x, lane = tid & 63, w = tid >> 6;  // w = 0..7
  const int col = lane & 15, quad = lane >> 4, quad4 = quad * 4;
  const int wm = (w & 3) * 32;   // 128 rows in 4 panels
  const int wn = (w >> 2) * 32;  // 64 cols in 2 panels

  // ---- fused Q projection: Q[128][64] = inputs-tile @ Wq-tile (K=512, BK=32)
  // A staged in PQ[.][0..31] (128 rows), W in PQ[0..63][40..71].
  {
    const int ar = tid >> 2;         // 0..127
    const int ak = (tid & 3) * 8;    // 0,8,16,24
    const bool wstage = tid < 256;   // ar = 0..63 for these

    f32x4 qacc[2][2];
#pragma unroll
    for (int i = 0; i < 2; ++i)
#pragma unroll
      for (int j = 0; j < 2; ++j) qacc[i][j] = f32x4{0.f, 0.f, 0.f, 0.f};

    const float* Ap = inp + (size_t)(b * 2048 + q0 + ar) * 512 + ak;
    const ushort* Wp = Wtq + (size_t)(h * 64 + ar) * 512 + ak;
    float4v a0p = *(const float4v*)Ap;
    float4v a1p = *(const float4v*)(Ap + 4);
    bf16x8 wp{};
    if (wstage) wp = *(const bf16x8*)Wp;

    for (int kt = 0; kt < 16; ++kt) {
      if (kt) __syncthreads();
      {
        union { ushort u[8]; bf16x8 v; } ap;
        ap.u[0] = f2b(a0p.x); ap.u[1] = f2b(a0p.y); ap.u[2] = f2b(a0p.z); ap.u[3] = f2b(a0p.w);
        ap.u[4] = f2b(a1p.x); ap.u[5] = f2b(a1p.y); ap.u[6] = f2b(a1p.z); ap.u[7] = f2b(a1p.w);
        *(bf16x8*)&PQ[ar][ak] = ap.v;
        if (wstage) *(bf16x8*)&PQ[ar][40 + ak] = wp;
      }
      if (kt < 15) {
        const int k1 = (kt + 1) * 32;
        a0p = *(const float4v*)(Ap + k1);
        a1p = *(const float4v*)(Ap + k1 + 4);
        if (wstage) wp = *(const bf16x8*)(Wp + k1);
      }
      __syncthreads();

      bf16x8 ah[2], wb[2];
#pragma unroll
      for (int i = 0; i < 2; ++i)
        ah[i] = *(const bf16x8*)&PQ[wm + i * 16 + col][quad * 8];
#pragma unroll
      for (int j = 0; j < 2; ++j)
        wb[j] = *(const bf16x8*)&PQ[wn + j * 16 + col][40 + quad * 8];
#pragma unroll
      for (int i = 0; i < 2; ++i)
#pragma unroll
        for (int j = 0; j < 2; ++j)
          qacc[i][j] = __builtin_amdgcn_mfma_f32_16x16x32_bf16(ah[i], wb[j], qacc[i][j], 0, 0, 0);
    }

    __syncthreads();  // all As/Ws reads done before PQ is overwritten with Q
#pragma unroll
    for (int i = 0; i < 2; ++i)
#pragma unroll
      for (int j = 0; j < 2; ++j)
#pragma unroll
        for (int r = 0; r < 4; ++r)
          PQ[wm + i * 16 + quad4 + r][wn + j * 16 + col] = f2b(qacc[i][j][r]);
    __syncthreads();
  }

  // grab Q B-frags from PQ[:][0..63]; PQ is never written again.
  const bf16x8 qb0 = *(const bf16x8*)&PQ[w * 16 + col][quad * 8];
  const bf16x8 qb1 = *(const bf16x8*)&PQ[w * 16 + col][32 + quad * 8];

  f32x4 oacc[4];
#pragma unroll
  for (int c = 0; c < 4; ++c) oacc[c] = f32x4{0.f, 0.f, 0.f, 0.f};
  f32x4 lacc = f32x4{0.f, 0.f, 0.f, 0.f};

  // ones B-fragment for l row-sums (bf16 1.0 = 0x3F80)
  union { ushort u[8]; bf16x8 v; } onesu;
#pragma unroll
  for (int j = 0; j < 8; ++j) onesu.u[j] = 0x3F80;
  const bf16x8 onesB = onesu.v;

  const uint4* kr = keep4 + (size_t)(b * 2048 + q0 + w * 16 + col) * 16;
  const ushort* Kb2 = Kbf + (size_t)bh * 2048 * 64;   // [k][d], row-major
  const ushort* Vb2 = Vtbf + (size_t)bh * 64 * 2048;  // [d][k], row-major

  // per-lane fragment offsets (elements)
  const int ko = col * 64 + quad * 8;    // + t*1024 (+32 for d-high half)
  const int vo = col * 2048 + quad * 8;  // + c*32768 + kb*32 (+ kt*128 via base)

  bf16x8 kf0[8], kf1[8], vf[4][4];
  uint4 kw = kr[0];
#pragma unroll
  for (int t = 0; t < 8; ++t) {
    kf0[t] = *(const bf16x8*)(Kb2 + ko + t * 1024);
    kf1[t] = *(const bf16x8*)(Kb2 + ko + t * 1024 + 32);
  }
#pragma unroll
  for (int kb = 0; kb < 4; ++kb)
#pragma unroll
    for (int c = 0; c < 4; ++c)
      vf[kb][c] = *(const bf16x8*)(Vb2 + vo + c * 32768 + kb * 32);

#pragma unroll 1
  for (int kt = 0; kt < 16; ++kt) {
    __builtin_amdgcn_s_barrier();  // loose lockstep for L1 reuse; no vmcnt drain

    uint4 kwn = kw;
    if (kt < 15) kwn = kr[kt + 1];

    // S^T: 128 k-rows x 16 q-cols per wave, K frags in registers
    f32x4 sc[8];
#pragma unroll
    for (int t = 0; t < 8; ++t) sc[t] = f32x4{0.f, 0.f, 0.f, 0.f};
#pragma unroll
    for (int t = 0; t < 8; ++t) {
      sc[t] = __builtin_amdgcn_mfma_f32_16x16x32_bf16(kf0[t], qb0, sc[t], 0, 0, 0);
      sc[t] = __builtin_amdgcn_mfma_f32_16x16x32_bf16(kf1[t], qb1, sc[t], 0, 0, 0);
    }

    // prefetch next K tile into regs (hides under softmax + PV)
    if (kt < 15) {
      const ushort* Kn = Kb2 + (kt + 1) * 8192;
#pragma unroll
      for (int t = 0; t < 8; ++t) {
        kf0[t] = *(const bf16x8*)(Kn + ko + t * 1024);
        kf1[t] = *(const bf16x8*)(Kn + ko + t * 1024 + 32);
      }
    }

    // softmax (static max) + in-register P redistribution + PV, fused per kb
    const uint mx_ = kw.x >> quad, my_ = kw.y >> quad, mz_ = kw.z >> quad, mw_ = kw.w >> quad;
#pragma unroll
    for (int kb = 0; kb < 4; ++kb) {
      uint Xa0, Xa1, Xb0, Xb1;
      {
        const int sh = 8 * kb;
        float p0 = ((mx_ >> sh) & 1u) ? exp2f(sc[2 * kb][0] * SL) : 0.f;
        float p1 = ((my_ >> sh) & 1u) ? exp2f(sc[2 * kb][1] * SL) : 0.f;
        float p2 = ((mz_ >> sh) & 1u) ? exp2f(sc[2 * kb][2] * SL) : 0.f;
        float p3 = ((mw_ >> sh) & 1u) ? exp2f(sc[2 * kb][3] * SL) : 0.f;
        __hip_bfloat162 lo = __float22bfloat162_rn(float2{p0, p1});
        __hip_bfloat162 hi = __float22bfloat162_rn(float2{p2, p3});
        Xa0 = *reinterpret_cast<uint*>(&lo);
        Xa1 = *reinterpret_cast<uint*>(&hi);
      }
      {
        const int sh = 8 * kb + 4;
        float p0 = ((mx_ >> sh) & 1u) ? exp2f(sc[2 * kb + 1][0] * SL) : 0.f;
        float p1 = ((my_ >> sh) & 1u) ? exp2f(sc[2 * kb + 1][1] * SL) : 0.f;
        float p2 = ((mz_ >> sh) & 1u) ? exp2f(sc[2 * kb + 1][2] * SL) : 0.f;
        float p3 = ((mw_ >> sh) & 1u) ? exp2f(sc[2 * kb + 1][3] * SL) : 0.f;
        __hip_bfloat162 lo = __float22bfloat162_rn(float2{p0, p1});
        __hip_bfloat162 hi = __float22bfloat162_rn(float2{p2, p3});
        Xb0 = *reinterpret_cast<uint*>(&lo);
        Xb1 = *reinterpret_cast<uint*>(&hi);
      }
      auto a32 = __builtin_amdgcn_permlane32_swap(Xa0, Xb0, false, false);
      auto a16 = __builtin_amdgcn_permlane16_swap(a32[0], a32[1], false, false);
      auto b32 = __builtin_amdgcn_permlane32_swap(Xa1, Xb1, false, false);
      auto b16 = __builtin_amdgcn_permlane16_swap(b32[0], b32[1], false, false);
      union { uint u[4]; bf16x8 v; } pu;
      pu.u[0] = a16[0]; pu.u[1] = b16[0]; pu.u[2] = a16[1]; pu.u[3] = b16[1];
      const bf16x8 pa = pu.v;
      lacc = __builtin_amdgcn_mfma_f32_16x16x32_bf16(pa, onesB, lacc, 0, 0, 0);
#pragma unroll
      for (int c = 0; c < 4; ++c)
        oacc[c] = __builtin_amdgcn_mfma_f32_16x16x32_bf16(pa, vf[kb][c], oacc[c], 0, 0, 0);
    }

    // prefetch next V tile into regs (hides under next QK)
    if (kt < 15) {
      const ushort* Vn = Vb2 + (kt + 1) * 128;
#pragma unroll
      for (int kb = 0; kb < 4; ++kb)
#pragma unroll
        for (int c = 0; c < 4; ++c)
          vf[kb][c] = *(const bf16x8*)(Vn + vo + c * 32768 + kb * 32);
    }
    kw = kwn;
  }

  // lacc[r] = l for q-row w*16+quad4+r (replicated across cols) — no shuffles
  float invO[4];
#pragma unroll
  for (int r = 0; r < 4; ++r) invO[r] = 1.f / lacc[r];
#pragma unroll
  for (int c = 0; c < 4; ++c)
#pragma unroll
    for (int r = 0; r < 4; ++r)
      Op[(size_t)(b * S + q0 + w * 16 + quad4 + r) * HD + h * D + c * 16 + col] =
          f2b(oacc[c][r] * invO[r]);
}

}  // namespace

extern "C" void kernel_launch(void* const* d_in, const int* in_sizes, int n_in,
                              void* d_out, int out_size, void* d_ws, size_t ws_size,
                              hipStream_t stream) {
  const float* inputs = (const float*)d_in[0];   // (B,S,E)
  const float* keys   = (const float*)d_in[1];   // (B,S,H,D)
  const float* values = (const float*)d_in[2];   // (B,S,H,D)
  const float* wq     = (const float*)d_in[3];   // (E, HD)
  const float* wo     = (const float*)d_in[4];   // (HD, E)
  const int*   maskp  = (const int*)d_in[5];     // (B,S,S) bool as int32
  float* out = (float*)d_out;                    // (B,S,E)

  // d_out (8 MB) doubles as scratch for K/V bf16 until proj_out overwrites it.
  ushort* Kbf  = (ushort*)d_out;                 // (B,H,S,D) bf16, 4 MB
  ushort* Vtbf = Kbf + (size_t)2097152;          // (B,H,D,S) bf16, 4 MB

  char* ws = (char*)d_ws;
  ushort* attnb = (ushort*)ws;                   // 4 MB
  uint4*  keep4 = (uint4*)(ws + (4 << 20));      // 1 MB
  ushort* Wtq   = (ushort*)(ws + (5 << 20));     // 0.5 MB
  ushort* Wto   = (ushort*)(ws + (5 << 20) + (512 << 10));  // 0.5 MB

  prep_fused_kernel<<<dim3(8832), dim3(256), 0, stream>>>(keys, values, wq, wo, maskp,
                                                          Kbf, Vtbf, Wtq, Wto, keep4);
  flash_attn_kernel<<<dim3(256), dim3(512), 0, stream>>>(inputs, Wtq, Kbf, Vtbf, keep4, attnb);
  proj_out_kernel<<<dim3(8, 64), dim3(256), 0, stream>>>(attnb, Wto, out);
}

// Round 4
// 160.969 us; speedup vs baseline: 1.4703x; 1.4703x over previous
//
#include <hip/hip_runtime.h>
#include <hip/hip_bf16.h>

namespace {

constexpr int B = 2, S = 2048, E = 512, H = 8, D = 64, HD = 512;
constexpr float SL = 0.125f * 1.44269504f;  // (1/sqrt(64)) * log2(e)
constexpr int PLD = 40;                     // proj LDS row stride (bf16)

typedef __attribute__((ext_vector_type(8))) short bf16x8;
typedef __attribute__((ext_vector_type(4))) unsigned short u16x4;
typedef __attribute__((ext_vector_type(4))) float f32x4;
typedef __attribute__((ext_vector_type(4))) float float4v;

__device__ __forceinline__ ushort f2b(float x) {
  __hip_bfloat16 h = __float2bfloat16(x);
  return *reinterpret_cast<const ushort*>(&h);
}

// ---------------------------------------------------------------------------
// Fused prep. blocks [0,512): K/V convert+transpose; [512,640): W transpose;
// [640,8832): mask -> ballot keep bits (4096 rows x 8 chunks = 32768 waves).
// keep layout: uint4 per (row, 128k-tile); component r bit i = keep(k=tile*128+4i+r).
__global__ __launch_bounds__(256) void prep_fused_kernel(
    const float* __restrict__ K, const float* __restrict__ V,
    const float* __restrict__ Wq, const float* __restrict__ Wo,
    const int* __restrict__ maskp,
    ushort* __restrict__ Kbf, ushort* __restrict__ Vtbf,
    ushort* __restrict__ Wtq, ushort* __restrict__ Wto,
    uint4* __restrict__ keep4) {
  const int bid = blockIdx.x;
  const int t = threadIdx.x;
  if (bid < 512) {
    __shared__ __align__(16) ushort Vn[64][76];
    const int kt = bid & 31;
    const int bh = bid >> 5;
    const int b = bh >> 3, h = bh & 7;
    const int k0 = kt * 64;
#pragma unroll
    for (int i = 0; i < 4; ++i) {
      int c = i * 256 + t;
      int kk = c >> 4, d4 = (c & 15) * 4;
      size_t g = ((size_t)(b * 2048 + k0 + kk) * 8 + h) * 64 + d4;
      float4v kv = *(const float4v*)(K + g);
      float4v vv = *(const float4v*)(V + g);
      u16x4 kp = {f2b(kv.x), f2b(kv.y), f2b(kv.z), f2b(kv.w)};
      u16x4 vp = {f2b(vv.x), f2b(vv.y), f2b(vv.z), f2b(vv.w)};
      *(u16x4*)(Kbf + ((size_t)(bh * 2048 + k0 + kk)) * 64 + d4) = kp;
      *(u16x4*)&Vn[kk][d4] = vp;
    }
    __syncthreads();
#pragma unroll
    for (int i = 0; i < 2; ++i) {
      int c = i * 256 + t;
      int kc8 = (c & 7) * 8, d = c >> 3;
      union { ushort u[8]; bf16x8 v; } p;
#pragma unroll
      for (int j = 0; j < 8; ++j) p.u[j] = Vn[kc8 + j][d];
      *(bf16x8*)(Vtbf + ((size_t)(bh * 64 + d)) * 2048 + k0 + kc8) = p.v;
    }
  } else if (bid < 640) {
    __shared__ __align__(16) ushort T[64][68];
    const int idx = bid - 512;
    const float* Wsrc = (idx >> 6) ? Wo : Wq;
    ushort* Wdst = (idx >> 6) ? Wto : Wtq;
    const int x = idx & 63;
    const int k0 = (x & 7) * 64, n0 = (x >> 3) * 64;
#pragma unroll
    for (int i = 0; i < 4; ++i) {
      int c = i * 256 + t;
      int kk = c >> 4, n4 = (c & 15) * 4;
      float4v v = *(const float4v*)(Wsrc + (size_t)(k0 + kk) * 512 + n0 + n4);
      u16x4 p = {f2b(v.x), f2b(v.y), f2b(v.z), f2b(v.w)};
      *(u16x4*)&T[kk][n4] = p;
    }
    __syncthreads();
#pragma unroll
    for (int i = 0; i < 2; ++i) {
      int c = i * 256 + t;
      int n = c >> 3, k8 = (c & 7) * 8;
      union { ushort u[8]; bf16x8 v; } p;
#pragma unroll
      for (int j = 0; j < 8; ++j) p.u[j] = T[k8 + j][n];
      *(bf16x8*)(Wdst + (size_t)(n0 + n) * 512 + k0 + k8) = p.v;
    }
  } else {
    // mask: wave per 256-k chunk of one row; 4096 rows x 8 chunks
    const int wid = (bid - 640) * 4 + (t >> 6);  // 0..32767
    const int row = wid >> 3, c = wid & 7;
    const int lane = t & 63;
    const int4 v = *((const int4*)(maskp + (size_t)row * 2048 + c * 256) + lane);
    unsigned long long bx = __ballot(v.x == 0);
    unsigned long long by = __ballot(v.y == 0);
    unsigned long long bz = __ballot(v.z == 0);
    unsigned long long bw = __ballot(v.w == 0);
    if (lane == 0)
      keep4[(size_t)row * 16 + c * 2] = uint4{(uint)bx, (uint)by, (uint)bz, (uint)bw};
    if (lane == 32)
      keep4[(size_t)row * 16 + c * 2 + 1] =
          uint4{(uint)(bx >> 32), (uint)(by >> 32), (uint)(bz >> 32), (uint)(bw >> 32)};
  }
}

// ---------------------------------------------------------------------------
// proj_out: out fp32 = attnb (bf16) @ Wo, pipelined LDS staging.
__global__ __launch_bounds__(256) void proj_out_kernel(
    const ushort* __restrict__ A, const ushort* __restrict__ Wt, float* __restrict__ C) {
  __shared__ __align__(16) ushort As[64][PLD];
  __shared__ __align__(16) ushort Ws[64][PLD];

  const int tid = threadIdx.x;
  const int lane = tid & 63;
  const int w = tid >> 6;
  const int col = lane & 15;
  const int quad = lane >> 4;
  const int m0 = blockIdx.y * 64;
  const int n0 = blockIdx.x * 64;
  const int wm = (w & 1) * 32;
  const int wn = (w >> 1) * 32;
  const int ar = tid >> 2;
  const int ak = (tid & 3) * 8;
  const int wn2 = tid >> 2;
  const int wkc = (tid & 3) * 8;

  f32x4 acc[2][2];
#pragma unroll
  for (int i = 0; i < 2; ++i)
#pragma unroll
    for (int j = 0; j < 2; ++j) acc[i][j] = f32x4{0.f, 0.f, 0.f, 0.f};

  const ushort* Ap = A + (size_t)(m0 + ar) * 512 + ak;
  const ushort* Wp = Wt + (size_t)(n0 + wn2) * 512 + wkc;
  bf16x8 apre = *(const bf16x8*)Ap;
  bf16x8 wp = *(const bf16x8*)Wp;

  for (int kt = 0; kt < 16; ++kt) {
    if (kt) __syncthreads();
    *(bf16x8*)&As[ar][ak] = apre;
    *(bf16x8*)&Ws[wn2][wkc] = wp;
    if (kt < 15) {
      const int k1 = (kt + 1) * 32;
      apre = *(const bf16x8*)(Ap + k1);
      wp = *(const bf16x8*)(Wp + k1);
    }
    __syncthreads();

    bf16x8 ah[2], wb[2];
#pragma unroll
    for (int i = 0; i < 2; ++i)
      ah[i] = *(const bf16x8*)&As[wm + i * 16 + col][quad * 8];
#pragma unroll
    for (int j = 0; j < 2; ++j)
      wb[j] = *(const bf16x8*)&Ws[wn + j * 16 + col][quad * 8];
#pragma unroll
    for (int i = 0; i < 2; ++i)
#pragma unroll
      for (int j = 0; j < 2; ++j)
        acc[i][j] = __builtin_amdgcn_mfma_f32_16x16x32_bf16(ah[i], wb[j], acc[i][j], 0, 0, 0);
  }

#pragma unroll
  for (int i = 0; i < 2; ++i)
#pragma unroll
    for (int j = 0; j < 2; ++j)
#pragma unroll
      for (int r = 0; r < 4; ++r)
        C[(size_t)(m0 + wm + i * 16 + (quad << 2) + r) * 512 + n0 + wn + j * 16 + col] =
            acc[i][j][r];
}

// ---------------------------------------------------------------------------
// Flash attention, 256 threads / 64 q-rows / block, K-SPLIT across waves:
// wave w owns k in [32w, 32w+32) of each 128-k tile, so the staged K and V
// tiles are each read from LDS exactly ONCE per block (vs 4x in the q-split).
// Q is hoisted fully into registers. Partial O/l per wave, LDS tree-reduced
// in the epilogue. Fused Q-projection prologue; permlane in-register P
// transpose (HW-verified in R2/R3).
__global__ __launch_bounds__(256, 2) void flash_attn_kernel(
    const float* __restrict__ inp, const ushort* __restrict__ Wtq,
    const ushort* __restrict__ Kbf, const ushort* __restrict__ Vtbf,
    const uint4* __restrict__ keep4, ushort* __restrict__ Op) {
  __shared__ __align__(16) union SM {
    struct { ushort Ks[128][72]; ushort Vt[64][136]; ushort PQ[64][72]; } m;
    struct { float red[3][64][68]; float lred[3][64]; } r;
  } sm;

  const int bid = blockIdx.x;
  const int qt = bid & 31;
  const int bh = bid >> 5;
  const int b = bh >> 3, h = bh & 7;
  const int q0 = qt * 64;
  const int tid = threadIdx.x, lane = tid & 63, w = tid >> 6;
  const int col = lane & 15, quad = lane >> 4, quad4 = quad * 4;
  const int wm = (w & 1) * 32;
  const int wn = (w >> 1) * 32;

  // ---- fused Q projection: Q[64][64] = inputs-tile @ Wq-tile (K=512, BK=32)
  {
    const int ar = tid >> 2;
    const int ak = (tid & 3) * 8;

    f32x4 qacc[2][2];
#pragma unroll
    for (int i = 0; i < 2; ++i)
#pragma unroll
      for (int j = 0; j < 2; ++j) qacc[i][j] = f32x4{0.f, 0.f, 0.f, 0.f};

    const float* Ap = inp + (size_t)(b * 2048 + q0 + ar) * 512 + ak;
    const ushort* Wp = Wtq + (size_t)(h * 64 + ar) * 512 + ak;
    float4v a0p = *(const float4v*)Ap;
    float4v a1p = *(const float4v*)(Ap + 4);
    bf16x8 wp = *(const bf16x8*)Wp;

    for (int kt = 0; kt < 16; ++kt) {
      if (kt) __syncthreads();
      {
        union { ushort u[8]; bf16x8 v; } ap;
        ap.u[0] = f2b(a0p.x); ap.u[1] = f2b(a0p.y); ap.u[2] = f2b(a0p.z); ap.u[3] = f2b(a0p.w);
        ap.u[4] = f2b(a1p.x); ap.u[5] = f2b(a1p.y); ap.u[6] = f2b(a1p.z); ap.u[7] = f2b(a1p.w);
        *(bf16x8*)&sm.m.PQ[ar][ak] = ap.v;
        *(bf16x8*)&sm.m.PQ[ar][40 + ak] = wp;
      }
      if (kt < 15) {
        const int k1 = (kt + 1) * 32;
        a0p = *(const float4v*)(Ap + k1);
        a1p = *(const float4v*)(Ap + k1 + 4);
        wp = *(const bf16x8*)(Wp + k1);
      }
      __syncthreads();

      bf16x8 ah[2], wb[2];
#pragma unroll
      for (int i = 0; i < 2; ++i)
        ah[i] = *(const bf16x8*)&sm.m.PQ[wm + i * 16 + col][quad * 8];
#pragma unroll
      for (int j = 0; j < 2; ++j)
        wb[j] = *(const bf16x8*)&sm.m.PQ[wn + j * 16 + col][40 + quad * 8];
#pragma unroll
      for (int i = 0; i < 2; ++i)
#pragma unroll
        for (int j = 0; j < 2; ++j)
          qacc[i][j] = __builtin_amdgcn_mfma_f32_16x16x32_bf16(ah[i], wb[j], qacc[i][j], 0, 0, 0);
    }

    __syncthreads();  // all As/Ws reads done before PQ is overwritten with Q
#pragma unroll
    for (int i = 0; i < 2; ++i)
#pragma unroll
      for (int j = 0; j < 2; ++j)
#pragma unroll
        for (int r = 0; r < 4; ++r)
          sm.m.PQ[wm + i * 16 + quad4 + r][wn + j * 16 + col] = f2b(qacc[i][j][r]);
    __syncthreads();
  }

  // hoist the FULL Q tile into registers: qb[j][half], j = q-16-tile, 32 VGPR
  bf16x8 qb[4][2];
#pragma unroll
  for (int j = 0; j < 4; ++j)
#pragma unroll
    for (int hf = 0; hf < 2; ++hf)
      qb[j][hf] = *(const bf16x8*)&sm.m.PQ[j * 16 + col][hf * 32 + quad * 8];

  f32x4 oacc[4][4];  // [q-tile j][d-tile c], partial over this wave's k
#pragma unroll
  for (int j = 0; j < 4; ++j)
#pragma unroll
    for (int c = 0; c < 4; ++c) oacc[j][c] = f32x4{0.f, 0.f, 0.f, 0.f};
  f32x4 lacc[4];
#pragma unroll
  for (int j = 0; j < 4; ++j) lacc[j] = f32x4{0.f, 0.f, 0.f, 0.f};

  // ones B-fragment for l row-sums (bf16 1.0 = 0x3F80)
  union { ushort u[8]; bf16x8 v; } onesu;
#pragma unroll
  for (int j = 0; j < 8; ++j) onesu.u[j] = 0x3F80;
  const bf16x8 onesB = onesu.v;

  const uint4* kr0 = keep4 + (size_t)(b * 2048 + q0 + col) * 16;  // +j*256 per q-tile
  const ushort* Kbase = Kbf + (size_t)bh * 2048 * 64;
  const ushort* Vbase = Vtbf + (size_t)bh * 64 * 2048;
  const int mshift = 8 * w + quad;  // bit index base for this wave's k-block

  bf16x8 kpre[4], vpre[4];
#pragma unroll
  for (int i = 0; i < 4; ++i) {
    int c = i * 256 + tid;
    kpre[i] = *(const bf16x8*)(Kbase + (size_t)c * 8);
    int d = c >> 4, k8 = (c & 15) * 8;
    vpre[i] = *(const bf16x8*)(Vbase + (size_t)d * 2048 + k8);
  }

  for (int kt = 0; kt < 16; ++kt) {
    if (kt) __syncthreads();
#pragma unroll
    for (int i = 0; i < 4; ++i) {
      int c = i * 256 + tid;
      *(bf16x8*)&sm.m.Ks[c >> 3][(c & 7) * 8] = kpre[i];
      int d = c >> 4, k8 = (c & 15) * 8;
      *(bf16x8*)&sm.m.Vt[d][k8] = vpre[i];
    }
    // keep rows for this kt: one uint4 per q-tile j (row q0+16j+col)
    uint4 kwj[4];
#pragma unroll
    for (int j = 0; j < 4; ++j) kwj[j] = kr0[j * 256 + kt];
    if (kt < 15) {
      const int k1 = (kt + 1) * 128;
#pragma unroll
      for (int i = 0; i < 4; ++i) {
        int c = i * 256 + tid;
        kpre[i] = *(const bf16x8*)(Kbase + (size_t)k1 * 64 + c * 8);
        int d = c >> 4, k8 = (c & 15) * 8;
        vpre[i] = *(const bf16x8*)(Vbase + (size_t)d * 2048 + k1 + k8);
      }
    }
    __syncthreads();

    // this wave's K slice: rows w*32 .. w*32+31 (2 k-tiles x 2 d-halves)
    bf16x8 ka[2][2];
#pragma unroll
    for (int t = 0; t < 2; ++t)
#pragma unroll
      for (int hf = 0; hf < 2; ++hf)
        ka[t][hf] = *(const bf16x8*)&sm.m.Ks[w * 32 + t * 16 + col][hf * 32 + quad * 8];

    // S^T: 32 k-rows x 64 q-cols per wave
    f32x4 sc[2][4];
#pragma unroll
    for (int t = 0; t < 2; ++t)
#pragma unroll
      for (int j = 0; j < 4; ++j) sc[t][j] = f32x4{0.f, 0.f, 0.f, 0.f};
#pragma unroll
    for (int t = 0; t < 2; ++t)
#pragma unroll
      for (int hf = 0; hf < 2; ++hf)
#pragma unroll
        for (int j = 0; j < 4; ++j)
          sc[t][j] = __builtin_amdgcn_mfma_f32_16x16x32_bf16(ka[t][hf], qb[j][hf], sc[t][j], 0, 0, 0);

    // this wave's V slice: k-depth w*32..+31, all 64 d
    bf16x8 vb[4];
#pragma unroll
    for (int c = 0; c < 4; ++c)
      vb[c] = *(const bf16x8*)&sm.m.Vt[c * 16 + col][w * 32 + quad * 8];

    // softmax (static max) + in-register P transpose + PV, per q-tile j
#pragma unroll
    for (int j = 0; j < 4; ++j) {
      const uint mx_ = kwj[j].x >> mshift, my_ = kwj[j].y >> mshift,
                 mz_ = kwj[j].z >> mshift, mw_ = kwj[j].w >> mshift;
      uint Xa0, Xa1, Xb0, Xb1;
      {  // t = 0: k = w*32 + 0..15
        float p0 = (mx_ & 1u) ? exp2f(sc[0][j][0] * SL) : 0.f;
        float p1 = (my_ & 1u) ? exp2f(sc[0][j][1] * SL) : 0.f;
        float p2 = (mz_ & 1u) ? exp2f(sc[0][j][2] * SL) : 0.f;
        float p3 = (mw_ & 1u) ? exp2f(sc[0][j][3] * SL) : 0.f;
        __hip_bfloat162 lo = __float22bfloat162_rn(float2{p0, p1});
        __hip_bfloat162 hi = __float22bfloat162_rn(float2{p2, p3});
        Xa0 = *reinterpret_cast<uint*>(&lo);
        Xa1 = *reinterpret_cast<uint*>(&hi);
      }
      {  // t = 1: k = w*32 + 16..31
        float p0 = ((mx_ >> 4) & 1u) ? exp2f(sc[1][j][0] * SL) : 0.f;
        float p1 = ((my_ >> 4) & 1u) ? exp2f(sc[1][j][1] * SL) : 0.f;
        float p2 = ((mz_ >> 4) & 1u) ? exp2f(sc[1][j][2] * SL) : 0.f;
        float p3 = ((mw_ >> 4) & 1u) ? exp2f(sc[1][j][3] * SL) : 0.f;
        __hip_bfloat162 lo = __float22bfloat162_rn(float2{p0, p1});
        __hip_bfloat162 hi = __float22bfloat162_rn(float2{p2, p3});
        Xb0 = *reinterpret_cast<uint*>(&lo);
        Xb1 = *reinterpret_cast<uint*>(&hi);
      }
      auto a32 = __builtin_amdgcn_permlane32_swap(Xa0, Xb0, false, false);
      auto a16 = __builtin_amdgcn_permlane16_swap(a32[0], a32[1], false, false);
      auto b32 = __builtin_amdgcn_permlane32_swap(Xa1, Xb1, false, false);
      auto b16 = __builtin_amdgcn_permlane16_swap(b32[0], b32[1], false, false);
      union { uint u[4]; bf16x8 v; } pu;
      pu.u[0] = a16[0]; pu.u[1] = b16[0]; pu.u[2] = a16[1]; pu.u[3] = b16[1];
      const bf16x8 pa = pu.v;
      lacc[j] = __builtin_amdgcn_mfma_f32_16x16x32_bf16(pa, onesB, lacc[j], 0, 0, 0);
#pragma unroll
      for (int c = 0; c < 4; ++c)
        oacc[j][c] = __builtin_amdgcn_mfma_f32_16x16x32_bf16(pa, vb[c], oacc[j][c], 0, 0, 0);
    }
  }

  // ---- epilogue: cross-wave reduction of partial O (red[d][q]) and l ----
  __syncthreads();  // last PV reads done; LDS union switches to .r
  if (w > 0) {
    const int wi = w - 1;
#pragma unroll
    for (int j = 0; j < 4; ++j)
#pragma unroll
      for (int c = 0; c < 4; ++c)
        *(f32x4*)&sm.r.red[wi][c * 16 + col][j * 16 + quad4] = oacc[j][c];
    if (col == 0)
#pragma unroll
      for (int j = 0; j < 4; ++j)
        *(f32x4*)&sm.r.lred[wi][j * 16 + quad4] = lacc[j];
  }
  __syncthreads();
  if (w == 0) {
#pragma unroll
    for (int j = 0; j < 4; ++j) {
#pragma unroll
      for (int c = 0; c < 4; ++c) {
        f32x4 s = oacc[j][c];
#pragma unroll
        for (int i = 0; i < 3; ++i)
          s += *(const f32x4*)&sm.r.red[i][c * 16 + col][j * 16 + quad4];
        oacc[j][c] = s;
      }
      f32x4 ls = lacc[j];
#pragma unroll
      for (int i = 0; i < 3; ++i)
        ls += *(const f32x4*)&sm.r.lred[i][j * 16 + quad4];
      lacc[j] = ls;
    }
    // publish final (unnormalized) O and l
#pragma unroll
    for (int j = 0; j < 4; ++j) {
#pragma unroll
      for (int c = 0; c < 4; ++c)
        *(f32x4*)&sm.r.red[0][c * 16 + col][j * 16 + quad4] = oacc[j][c];
      if (col == 0) *(f32x4*)&sm.r.lred[0][j * 16 + quad4] = lacc[j];
    }
  }
  __syncthreads();

  // cooperative normalized store: thread -> (q = tid>>2, 16 d's)
  {
    const int q = tid >> 2, d0 = (tid & 3) * 16;
    const float inv = 1.f / sm.r.lred[0][q];
    union { ushort u[16]; bf16x8 v[2]; } ob;
#pragma unroll
    for (int dd = 0; dd < 16; ++dd)
      ob.u[dd] = f2b(sm.r.red[0][d0 + dd][q] * inv);
    ushort* dst = Op + (size_t)(b * S + q0 + q) * HD + h * D + d0;
    *(bf16x8*)dst = ob.v[0];
    *(bf16x8*)(dst + 8) = ob.v[1];
  }
}

}  // namespace

extern "C" void kernel_launch(void* const* d_in, const int* in_sizes, int n_in,
                              void* d_out, int out_size, void* d_ws, size_t ws_size,
                              hipStream_t stream) {
  const float* inputs = (const float*)d_in[0];   // (B,S,E)
  const float* keys   = (const float*)d_in[1];   // (B,S,H,D)
  const float* values = (const float*)d_in[2];   // (B,S,H,D)
  const float* wq     = (const float*)d_in[3];   // (E, HD)
  const float* wo     = (const float*)d_in[4];   // (HD, E)
  const int*   maskp  = (const int*)d_in[5];     // (B,S,S) bool as int32
  float* out = (float*)d_out;                    // (B,S,E)

  // d_out (8 MB) doubles as scratch for K/V bf16 until proj_out overwrites it.
  ushort* Kbf  = (ushort*)d_out;                 // (B,H,S,D) bf16, 4 MB
  ushort* Vtbf = Kbf + (size_t)2097152;          // (B,H,D,S) bf16, 4 MB

  char* ws = (char*)d_ws;
  ushort* attnb = (ushort*)ws;                   // 4 MB
  uint4*  keep4 = (uint4*)(ws + (4 << 20));      // 1 MB
  ushort* Wtq   = (ushort*)(ws + (5 << 20));     // 0.5 MB
  ushort* Wto   = (ushort*)(ws + (5 << 20) + (512 << 10));  // 0.5 MB

  prep_fused_kernel<<<dim3(8832), dim3(256), 0, stream>>>(keys, values, wq, wo, maskp,
                                                          Kbf, Vtbf, Wtq, Wto, keep4);
  flash_attn_kernel<<<dim3(512), dim3(256), 0, stream>>>(inputs, Wtq, Kbf, Vtbf, keep4, attnb);
  proj_out_kernel<<<dim3(8, 64), dim3(256), 0, stream>>>(attnb, Wto, out);
}